// Round 1
// baseline (376.402 us; speedup 1.0000x reference)
//
#include <hip/hip_runtime.h>
#include <stdint.h>

// out[b,d,m] = (sum_n seg[b,d,n]*Wt[b,m,n]) / (sum_n Wt[b,m,n]),  Wt = W*(W>0.85)
// bs=4, d=16, n=4096. W = 268 MB read once -> memory floor ~43 us kernel.
//
// R5: counted-vmcnt pipeline (T3/T4). R4's __syncthreads() emitted
// s_waitcnt vmcnt(0) before every barrier, draining the W+seg prefetch queue
// every chunk (~2 TB/s effective). Now: raw s_barrier + manual
// s_waitcnt vmcnt(8) — each chunk is exactly 8 vmem ops (4 global_load_lds
// + 4 W dwordx4), so vmcnt(8) retires chunk c while chunk c+1 stays in
// flight ACROSS the barrier. Prefetch depth 2 on both streams; 4 LDS
// buffers (64 KB) so all buffer/reg-set indices are compile-time constants
// (runtime-indexed reg arrays go to scratch). Numerics bit-identical to R4.

typedef float v4f __attribute__((ext_vector_type(4)));

#define N_DIM 4096
#define D_DIM 16
#define THRESH 0.85f
#define RPW 4                  // rows per wave; block = 4 waves = 16 rows
#define CHUNK 256              // n per chunk (64 lanes x float4)
#define NCHUNK (N_DIM / CHUNK) // 16

__global__ __launch_bounds__(256) void regu_kernel(
    const float* __restrict__ seg,   // [4][16][4096]
    const float* __restrict__ W,     // [4][4096][4096]
    float* __restrict__ out)         // [4][16][4096]
{
    __shared__ float stile[4][D_DIM * CHUNK];   // 4 x 16 KB seg tiles = 64 KB

    const int lane = threadIdx.x & 63;
    const int wv   = threadIdx.x >> 6;
    const int row0 = blockIdx.x * 16 + wv * RPW;   // [0, 16384)
    const int b  = row0 >> 12;
    const int m0 = row0 & (N_DIM - 1);

    const float* Wp   = W   + ((size_t)b * N_DIM + m0) * N_DIM + lane * 4;
    const float* segb = seg + (size_t)b * D_DIM * N_DIM;

    float acc[RPW * D_DIM];                 // acc[r*16+d]
    float rowsum[RPW] = {0.f, 0.f, 0.f, 0.f};
#pragma unroll
    for (int i = 0; i < RPW * D_DIM; ++i) acc[i] = 0.f;

    // stage chunk c of seg (16 rows x 1 KB) into stile[sb]; wave wv stages
    // rows wv*4..wv*4+3. LDS dest is wave-uniform row base (HW adds lane*16).
    // 4 vmem ops per wave per chunk.
#define STAGE(c, sb)                                                          \
    do {                                                                      \
        _Pragma("unroll")                                                     \
        for (int j = 0; j < 4; ++j) {                                         \
            const int d_ = wv * 4 + j;                                        \
            const float* g_ = segb + (size_t)d_ * N_DIM + (size_t)(c) * CHUNK + lane * 4; \
            __builtin_amdgcn_global_load_lds(                                 \
                (const __attribute__((address_space(1))) uint32_t*)g_,        \
                (__attribute__((address_space(3))) uint32_t*)&stile[sb][d_ * CHUNK], \
                16, 0, 0);                                                    \
        }                                                                     \
    } while (0)

    // 4 vmem ops per wave per chunk (one dwordx4 per row)
#define LOADW(dst, c)                                                         \
    do {                                                                      \
        const float* p_ = Wp + (size_t)(c) * CHUNK;                           \
        _Pragma("unroll")                                                     \
        for (int r = 0; r < RPW; ++r)                                         \
            dst[r] = __builtin_nontemporal_load(                              \
                (const v4f*)(p_ + (size_t)r * N_DIM));                        \
    } while (0)

    v4f wR0[RPW], wR1[RPW];   // two named W reg sets (even/odd chunks)

    // one chunk: threshold W regs, rowsum, FMA against LDS seg tile.
    // sb is a literal at every call site -> addresses fold at compile time.
    auto compute = [&](const v4f (&w_in)[RPW], const int sb) {
        v4f w[RPW];
#pragma unroll
        for (int r = 0; r < RPW; ++r) {
            v4f v = w_in[r];
            v.x = (v.x > THRESH) ? v.x : 0.f;
            v.y = (v.y > THRESH) ? v.y : 0.f;
            v.z = (v.z > THRESH) ? v.z : 0.f;
            v.w = (v.w > THRESH) ? v.w : 0.f;
            w[r] = v;
            rowsum[r] += (v.x + v.y) + (v.z + v.w);
        }
#pragma unroll
        for (int d = 0; d < D_DIM; ++d) {
            const v4f s = *(const v4f*)&stile[sb][d * CHUNK + lane * 4];
#pragma unroll
            for (int r = 0; r < RPW; ++r) {
                acc[r * D_DIM + d] += w[r].x * s.x;
                acc[r * D_DIM + d] += w[r].y * s.y;
                acc[r * D_DIM + d] += w[r].z * s.z;
                acc[r * D_DIM + d] += w[r].w * s.w;
            }
        }
    };

    // prologue: chunks 0 and 1 in flight. Empty asm pins chunk-group issue
    // order so the 8-per-chunk vmcnt ledger holds.
    STAGE(0, 0); LOADW(wR0, 0);
    asm volatile("" ::: "memory");
    STAGE(1, 1); LOADW(wR1, 1);

    // Per phase (chunk c): wait until chunk c's 8 vmem ops retired (chunk
    // c+1's 8 stay in flight -> vmcnt(8)); barrier so all waves' stages of
    // chunk c are visible; issue stage(c+2) into buffer last read at c-2
    // (two barriers ago -> safe); compute(c); refill this W reg set with
    // chunk c+2 (WAR on regs keeps it after compute). Main loop never
    // drains vmcnt to 0.
#define PHASE(cexp, sb, wname, sb2)                                  \
    do {                                                             \
        const int c_ = (cexp);                                       \
        if (c_ < NCHUNK - 1)                                         \
            asm volatile("s_waitcnt vmcnt(8)" ::: "memory");         \
        else                                                         \
            asm volatile("s_waitcnt vmcnt(0)" ::: "memory");         \
        __builtin_amdgcn_s_barrier();                                \
        if (c_ + 2 < NCHUNK) STAGE(c_ + 2, sb2);                     \
        compute(wname, sb);                                          \
        if (c_ + 2 < NCHUNK) LOADW(wname, c_ + 2);                   \
    } while (0)

    for (int cc = 0; cc < NCHUNK; cc += 4) {
        PHASE(cc + 0, 0, wR0, 2);
        PHASE(cc + 1, 1, wR1, 3);
        PHASE(cc + 2, 2, wR0, 0);
        PHASE(cc + 3, 3, wR1, 1);
    }

#undef PHASE
#undef LOADW
#undef STAGE

    // scatter-reduce 64 partials: after 6 steps lane l holds the total for
    // index j = bitrev6(l)  (verified numerically in R2/R3)
#pragma unroll
    for (int k = 0; k < 6; ++k) {
        const int S = 32 >> k;
        const bool up = (lane >> k) & 1;
#pragma unroll
        for (int j = 0; j < S; ++j) {
            const float mine = up ? acc[j + S] : acc[j];
            const float send = up ? acc[j] : acc[j + S];
            acc[j] = mine + __shfl_xor(send, 1 << k, 64);
        }
    }

#pragma unroll
    for (int r = 0; r < RPW; ++r) {
        float s = rowsum[r];
#pragma unroll
        for (int off = 1; off < 64; off <<= 1) s += __shfl_xor(s, off, 64);
        rowsum[r] = s;
    }

    const int j = __brev((unsigned)lane) >> 26;   // bitrev6
    const int r = j >> 4;
    const int d = j & 15;
    const float inv = 1.0f / (r < 2 ? (r == 0 ? rowsum[0] : rowsum[1])
                                    : (r == 2 ? rowsum[2] : rowsum[3]));
    out[((size_t)b * D_DIM + d) * N_DIM + (m0 + r)] = acc[0] * inv;
}

extern "C" void kernel_launch(void* const* d_in, const int* in_sizes, int n_in,
                              void* d_out, int out_size, void* d_ws, size_t ws_size,
                              hipStream_t stream) {
    const float* seg = (const float*)d_in[0];   // [4,16,64,64] fp32
    const float* W   = (const float*)d_in[1];   // [4,4096,4096] fp32
    float* out = (float*)d_out;                 // [4,16,64,64] fp32

    // 16384 rows / (4 waves x 4 rows) = 1024 blocks
    regu_kernel<<<1024, 256, 0, stream>>>(seg, W, out);
}